// Round 5
// baseline (306.857 us; speedup 1.0000x reference)
//
#include <hip/hip_runtime.h>

// ---------------------------------------------------------------------------
// SpectralEncoder: ChebConv(K=4) x2 + mu/logvar heads.  bf16 features, MFMA
// GEMMs, wave-per-node gather props, folded Chebyshev weights.
// R4: 4-way sharded atomics (stride-N layout) for deg/cnt to break 32B-sector
//     serialization at the memory-side atomic units; shard-local pos + base4.
// ---------------------------------------------------------------------------

typedef __bf16 bf16x8 __attribute__((ext_vector_type(8)));
typedef float f32x4 __attribute__((ext_vector_type(4)));
typedef unsigned int uint32;
typedef unsigned short ushort16;

__device__ inline ushort16 f2bf(float f) {            // RNE fp32 -> bf16
    uint32 x = __float_as_uint(f);
    uint32 r = x + 0x7fffu + ((x >> 16) & 1u);
    return (ushort16)(r >> 16);
}
__device__ inline float bflo(uint32 v) { return __uint_as_float(v << 16); }
__device__ inline float bfhi(uint32 v) { return __uint_as_float(v & 0xffff0000u); }

// ---------------- graph preprocessing --------------------------------------
// sharded deg/cnt atomics; pos[e] = rank within (dst, shard) bucket.

__global__ void k_deg_cnt(const int* __restrict__ src, const int* __restrict__ dst,
                          const float* __restrict__ ew, float* __restrict__ deg4,
                          int* __restrict__ cnt4, int* __restrict__ pos, int E, int N) {
    int e = blockIdx.x * blockDim.x + threadIdx.x;
    if (e >= E) return;
    int sh = (e & 3) * N;
    atomicAdd(&deg4[sh + src[e]], ew[e]);
    pos[e] = atomicAdd(&cnt4[sh + dst[e]], 1);
}

// --- scan phase A: per-node totals over 4 shards, block-local prefix -------
__global__ void k_scan_blk(const int* __restrict__ cnt4, int* __restrict__ row_ptr,
                           int* __restrict__ blk_sums, int N) {
    __shared__ int wsum[4];
    const int tid = threadIdx.x;
    const int base = blockIdx.x * 1024 + tid * 4;
    int4 v = make_int4(0, 0, 0, 0);
    #pragma unroll
    for (int s = 0; s < 4; ++s) {
        const int* c = cnt4 + s * N;
        if (base + 3 < N) {
            int4 u = *(const int4*)&c[base];
            v.x += u.x; v.y += u.y; v.z += u.z; v.w += u.w;
        } else {
            if (base + 0 < N) v.x += c[base + 0];
            if (base + 1 < N) v.y += c[base + 1];
            if (base + 2 < N) v.z += c[base + 2];
        }
    }
    const int tsum = v.x + v.y + v.z + v.w;
    const int lane = tid & 63;
    const int wv = tid >> 6;
    int incl = tsum;
    #pragma unroll
    for (int off = 1; off < 64; off <<= 1) {
        int t = __shfl_up(incl, off);
        if (lane >= off) incl += t;
    }
    if (lane == 63) wsum[wv] = incl;
    __syncthreads();
    int woff = 0;
    #pragma unroll
    for (int w = 0; w < 4; ++w) if (w < wv) woff += wsum[w];
    const int excl = woff + incl - tsum;
    if (base + 0 < N) row_ptr[base + 0] = excl;
    if (base + 1 < N) row_ptr[base + 1] = excl + v.x;
    if (base + 2 < N) row_ptr[base + 2] = excl + v.x + v.y;
    if (base + 3 < N) row_ptr[base + 3] = excl + v.x + v.y + v.z;
    if (tid == 255) blk_sums[blockIdx.x] = woff + incl;
}

// --- scan phase B: one wave scans block totals (nblk <= 64) ----------------
__global__ void k_scan_top(int* __restrict__ blk_sums, int* __restrict__ row_ptr,
                           int nblk, int N) {
    const int lane = threadIdx.x;
    int v = (lane < nblk) ? blk_sums[lane] : 0;
    int incl = v;
    #pragma unroll
    for (int off = 1; off < 64; off <<= 1) {
        int t = __shfl_up(incl, off);
        if (lane >= off) incl += t;
    }
    if (lane < nblk) blk_sums[lane] = incl - v;
    if (lane == 63) row_ptr[N] = incl;
}

// --- scan phase C: global row_ptr, per-node shard bases, dis ---------------
__global__ void k_fix_dis(int* __restrict__ row_ptr, const int* __restrict__ blk_sums,
                          const int* __restrict__ cnt4, int4* __restrict__ base4,
                          const float* __restrict__ deg4, float* __restrict__ dis, int N) {
    int i = blockIdx.x * blockDim.x + threadIdx.x;
    if (i >= N) return;
    int rp = row_ptr[i] + blk_sums[i >> 10];
    row_ptr[i] = rp;
    int c0 = cnt4[i], c1 = cnt4[N + i], c2 = cnt4[2 * N + i];
    base4[i] = make_int4(rp, rp + c0, rp + c0 + c1, rp + c0 + c1 + c2);
    float d = deg4[i] + deg4[N + i] + deg4[2 * N + i] + deg4[3 * N + i];
    dis[i] = d > 0.f ? rsqrtf(fmaxf(d, 1e-12f)) : 0.f;
}

// --- atomic-free scatter: csr[base4[dst][shard]+pos] = {src, w_bits} -------
__global__ void k_scatter(const int* __restrict__ src, const int* __restrict__ dst,
                          const float* __restrict__ ew, const float* __restrict__ dis,
                          const int4* __restrict__ base4, const int* __restrict__ pos,
                          int2* __restrict__ csr, int E) {
    int e = blockIdx.x * blockDim.x + threadIdx.x;
    if (e >= E) return;
    int s = src[e], d = dst[e];
    float wv = -dis[s] * ew[e] * dis[d];
    int4 b = base4[d];
    int sh = e & 3;
    int bb = (sh == 0) ? b.x : (sh == 1) ? b.y : (sh == 2) ? b.z : b.w;
    csr[bb + pos[e]] = make_int2(s, __float_as_int(wv));
}

// ---------------- feature concat -> bf16 -----------------------------------

__global__ void k_concat_bf16(const float* __restrict__ x, const float* __restrict__ pe,
                              uint32* __restrict__ h, int N) {
    int i = blockIdx.x * blockDim.x + threadIdx.x;   // bf16-pair index
    if (i >= N * 64) return;
    int node = i >> 6, p = i & 63;
    float f0, f1;
    if (p < 56) { f0 = x[node * 112 + p * 2]; f1 = x[node * 112 + p * 2 + 1]; }
    else { int q = (p - 56) * 2; f0 = pe[node * 16 + q]; f1 = pe[node * 16 + q + 1]; }
    h[i] = (uint32)f2bf(f0) | ((uint32)f2bf(f1) << 16);
}

// ---------------- weight packing (fused, recurrence-transformed) -----------
// Layer transform (exact fp32): out = h(W0-W2) + Ph(W1-3W3) + P^2h(2W2) + P^3h(4W3)
// B-frag (16x16x32): lane l holds B[k=(l>>4)*8+j][col], j=0..7.

__device__ inline float wtrans(const float* __restrict__ W, int kb, size_t o) {
    switch (kb) {
        case 0:  return W[o] - W[o + 32768];
        case 1:  return W[o + 16384] - 3.f * W[o + 49152];
        case 2:  return 2.f * W[o + 32768];
        default: return 4.f * W[o + 49152];
    }
}

__global__ void k_pack_all(const float* __restrict__ W1, const float* __restrict__ W2,
                           const float* __restrict__ Wm, const float* __restrict__ Wl,
                           ushort16* __restrict__ W1p, ushort16* __restrict__ W2p,
                           ushort16* __restrict__ WHp) {
    int t = blockIdx.x * blockDim.x + threadIdx.x;
    uint32 v[8];
    if (t < 16384) {   // layer packs: 2 x 16 ks x 8 c x 64 lanes
        const float* W = (t < 8192) ? W1 : W2;
        ushort16* Wp = (t < 8192) ? W1p : W2p;
        int tt = t & 8191;
        int l = tt & 63, c = (tt >> 6) & 7, ks = tt >> 9;
        int kb = ks >> 2;
        int r0 = (ks & 3) * 32 + (l >> 4) * 8;
        int col = c * 16 + (l & 15);
        #pragma unroll
        for (int j = 0; j < 8; ++j)
            v[j] = f2bf(wtrans(W, kb, (size_t)(r0 + j) * 128 + col));
        uint4 o;
        o.x = v[0] | (v[1] << 16); o.y = v[2] | (v[3] << 16);
        o.z = v[4] | (v[5] << 16); o.w = v[6] | (v[7] << 16);
        *(uint4*)(Wp + (size_t)tt * 8) = o;
    } else if (t < 16384 + 2048) {   // head pack: cols = [mu | lv]
        int tt = t - 16384;
        int l = tt & 63, c = (tt >> 6) & 7, ks = tt >> 9;
        int k0 = ks * 32 + (l >> 4) * 8;
        int cc = c * 16 + (l & 15);
        const float* Ws = (cc < 64) ? Wm : Wl;
        int col = cc & 63;
        #pragma unroll
        for (int j = 0; j < 8; ++j) v[j] = f2bf(Ws[(size_t)(k0 + j) * 64 + col]);
        uint4 o;
        o.x = v[0] | (v[1] << 16); o.y = v[2] | (v[3] << 16);
        o.z = v[4] | (v[5] << 16); o.w = v[6] | (v[7] << 16);
        *(uint4*)(WHp + (size_t)tt * 8) = o;
    }
}

// ---------------- pure gather prop: out = P * tin  (bf16 features) ---------

__global__ void k_prop(const uint32* __restrict__ tin, const int2* __restrict__ csr,
                       const int* __restrict__ row_ptr, uint32* __restrict__ out, int N) {
    int wid = (blockIdx.x * blockDim.x + threadIdx.x) >> 6;
    int lane = threadIdx.x & 63;
    if (wid >= N) return;
    int beg = row_ptr[wid], end = row_ptr[wid + 1];
    float ax = 0.f, ay = 0.f;
    for (int base = beg; base < end; base += 64) {
        int m = end - base; if (m > 64) m = 64;
        int2 ev = (lane < m) ? csr[base + lane] : make_int2(0, 0);
        for (int j = 0; j < m; j += 8) {
            #pragma unroll
            for (int u = 0; u < 8; ++u) {       // pad lanes have w=0
                int s = __shfl(ev.x, j + u);
                float w = __uint_as_float(__shfl(ev.y, j + u));
                uint32 v = tin[(size_t)s * 64 + lane];
                ax = fmaf(w, bflo(v), ax); ay = fmaf(w, bfhi(v), ay);
            }
        }
    }
    out[(size_t)wid * 64 + lane] = (uint32)f2bf(ax) | ((uint32)f2bf(ay) << 16);
}

// ---------------- MFMA GEMM: C[N,128] = relu(sum_t T_t @ W_t + b), K=512 ---

template<bool RELU>
__launch_bounds__(256)
__global__ void k_mfma_gemm512(const ushort16* __restrict__ t0, const ushort16* __restrict__ t1,
                               const ushort16* __restrict__ t2, const ushort16* __restrict__ t3,
                               const ushort16* __restrict__ Wp, const float* __restrict__ bias,
                               ushort16* __restrict__ C, int N) {
    const int lane = threadIdx.x & 63;
    const int wave = threadIdx.x >> 6;
    const int brow = blockIdx.x * 128 + wave * 32;
    int r0 = brow + (lane & 15);
    int r1 = r0 + 16;
    if (r0 >= N) r0 = N - 1;
    if (r1 >= N) r1 = N - 1;
    const int kg8 = (lane >> 4) * 8;
    f32x4 acc[2][8] = {};
    #pragma unroll
    for (int t = 0; t < 4; ++t) {
        const ushort16* __restrict__ A = (t == 0) ? t0 : (t == 1) ? t1 : (t == 2) ? t2 : t3;
        const ushort16* a0p = A + (size_t)r0 * 128 + kg8;
        const ushort16* a1p = A + (size_t)r1 * 128 + kg8;
        #pragma unroll
        for (int ks2 = 0; ks2 < 4; ++ks2) {
            bf16x8 a0 = *(const bf16x8*)(a0p + ks2 * 32);
            bf16x8 a1 = *(const bf16x8*)(a1p + ks2 * 32);
            const ushort16* bp = Wp + (size_t)((t * 4 + ks2) * 8 * 64 + lane) * 8;
            #pragma unroll
            for (int c = 0; c < 8; ++c) {
                bf16x8 b = *(const bf16x8*)(bp + c * 512);
                acc[0][c] = __builtin_amdgcn_mfma_f32_16x16x32_bf16(a0, b, acc[0][c], 0, 0, 0);
                acc[1][c] = __builtin_amdgcn_mfma_f32_16x16x32_bf16(a1, b, acc[1][c], 0, 0, 0);
            }
        }
    }
    const int col0 = lane & 15;
    const int rj = (lane >> 4) * 4;
    #pragma unroll
    for (int m = 0; m < 2; ++m) {
        #pragma unroll
        for (int c = 0; c < 8; ++c) {
            float bv = bias[c * 16 + col0];
            #pragma unroll
            for (int j = 0; j < 4; ++j) {
                int row = brow + m * 16 + rj + j;
                if (row < N) {
                    float v = acc[m][c][j] + bv;
                    if (RELU) v = fmaxf(v, 0.f);
                    C[(size_t)row * 128 + c * 16 + col0] = f2bf(v);
                }
            }
        }
    }
}

// ---------------- fused heads via MFMA: [N,128]@[128,128], cols=[mu|lv] ----

__launch_bounds__(256)
__global__ void k_mfma_head(const ushort16* __restrict__ A, const ushort16* __restrict__ Wp,
                            const float* __restrict__ bm, const float* __restrict__ bl,
                            float* __restrict__ out, int N) {
    const int lane = threadIdx.x & 63;
    const int wave = threadIdx.x >> 6;
    const int brow = blockIdx.x * 128 + wave * 32;
    int r0 = brow + (lane & 15);
    int r1 = r0 + 16;
    if (r0 >= N) r0 = N - 1;
    if (r1 >= N) r1 = N - 1;
    const int kg8 = (lane >> 4) * 8;
    f32x4 acc[2][8] = {};
    const ushort16* a0p = A + (size_t)r0 * 128 + kg8;
    const ushort16* a1p = A + (size_t)r1 * 128 + kg8;
    #pragma unroll
    for (int ks = 0; ks < 4; ++ks) {
        bf16x8 a0 = *(const bf16x8*)(a0p + ks * 32);
        bf16x8 a1 = *(const bf16x8*)(a1p + ks * 32);
        const ushort16* bp = Wp + (size_t)(ks * 8 * 64 + lane) * 8;
        #pragma unroll
        for (int c = 0; c < 8; ++c) {
            bf16x8 b = *(const bf16x8*)(bp + c * 512);
            acc[0][c] = __builtin_amdgcn_mfma_f32_16x16x32_bf16(a0, b, acc[0][c], 0, 0, 0);
            acc[1][c] = __builtin_amdgcn_mfma_f32_16x16x32_bf16(a1, b, acc[1][c], 0, 0, 0);
        }
    }
    const int col0 = lane & 15;
    const int rj = (lane >> 4) * 4;
    #pragma unroll
    for (int m = 0; m < 2; ++m) {
        #pragma unroll
        for (int c = 0; c < 8; ++c) {
            int gcol = (c & 3) * 16 + col0;
            float bv = (c < 4) ? bm[gcol] : bl[gcol];
            size_t hoff = (c < 4) ? 0 : (size_t)N * 64;
            #pragma unroll
            for (int j = 0; j < 4; ++j) {
                int row = brow + m * 16 + rj + j;
                if (row < N)
                    out[hoff + (size_t)row * 64 + gcol] = acc[m][c][j] + bv;
            }
        }
    }
}

// ---------------------------------------------------------------------------

extern "C" void kernel_launch(void* const* d_in, const int* in_sizes, int n_in,
                              void* d_out, int out_size, void* d_ws, size_t ws_size,
                              hipStream_t stream) {
    const float* x   = (const float*)d_in[0];
    const int*   ei  = (const int*)d_in[1];
    const float* pe  = (const float*)d_in[2];
    const float* ew  = (const float*)d_in[3];
    const float* W1  = (const float*)d_in[4];
    const float* b1  = (const float*)d_in[5];
    const float* W2  = (const float*)d_in[6];
    const float* b2  = (const float*)d_in[7];
    const float* Wmu = (const float*)d_in[8];
    const float* bmu = (const float*)d_in[9];
    const float* Wlv = (const float*)d_in[10];
    const float* blv = (const float*)d_in[11];

    const int N = in_sizes[0] / 112;
    const int E = in_sizes[1] / 2;
    const int* src = ei;
    const int* dst = ei + E;

    char* ws = (char*)d_ws;
    size_t off = 0;
    auto alloc = [&](size_t bytes) -> char* {
        char* p = ws + off;
        off = (off + bytes + 255) & ~(size_t)255;
        return p;
    };
    float* deg4    = (float*)alloc((size_t)N * 16);
    int*   cnt4    = (int*)  alloc((size_t)N * 16);
    float* dis     = (float*)alloc((size_t)N * 4);
    int*   row_ptr = (int*)  alloc((size_t)(N + 1) * 4);
    int4*  base4   = (int4*) alloc((size_t)N * 16);
    int*   blk_sums= (int*)  alloc((size_t)256 * 4);
    int*   pos     = (int*)  alloc((size_t)E * 4);
    int2*  csr     = (int2*) alloc((size_t)E * 8);
    ushort16* W1p  = (ushort16*)alloc((size_t)512 * 128 * 2);
    ushort16* W2p  = (ushort16*)alloc((size_t)512 * 128 * 2);
    ushort16* WHp  = (ushort16*)alloc((size_t)128 * 128 * 2);
    ushort16* B0 = (ushort16*)alloc((size_t)N * 128 * 2);
    ushort16* B1 = (ushort16*)alloc((size_t)N * 128 * 2);
    ushort16* B2 = (ushort16*)alloc((size_t)N * 128 * 2);
    ushort16* B3 = (ushort16*)alloc((size_t)N * 128 * 2);
    ushort16* B4 = (ushort16*)alloc((size_t)N * 128 * 2);

    hipMemsetAsync(deg4, 0, (size_t)N * 16, stream);
    hipMemsetAsync(cnt4, 0, (size_t)N * 16, stream);

    const int eb = (E + 255) / 256;
    const int nb = (N + 255) / 256;
    const int pb = (N + 3) / 4;          // wave-per-node, 4 waves/block
    const int gb = (N + 127) / 128;      // 128 rows/block MFMA tiles
    const int nblk = (N + 1023) / 1024;  // 49 for N=50000 (<= 64 required)

    k_deg_cnt<<<eb, 256, 0, stream>>>(src, dst, ew, deg4, cnt4, pos, E, N);
    k_scan_blk<<<nblk, 256, 0, stream>>>(cnt4, row_ptr, blk_sums, N);
    k_scan_top<<<1, 64, 0, stream>>>(blk_sums, row_ptr, nblk, N);
    k_fix_dis<<<nb, 256, 0, stream>>>(row_ptr, blk_sums, cnt4, base4, deg4, dis, N);
    k_scatter<<<eb, 256, 0, stream>>>(src, dst, ew, dis, base4, pos, csr, E);
    k_concat_bf16<<<(N * 64 + 255) / 256, 256, 0, stream>>>(x, pe, (uint32*)B0, N);
    k_pack_all<<<(16384 + 2048 + 255) / 256, 256, 0, stream>>>(W1, W2, Wmu, Wlv, W1p, W2p, WHp);

    // layer 1: Y1=P*B0, Y2=P*Y1, Y3=P*Y2 -> gemm(transformed W1) -> relu -> B4
    k_prop<<<pb, 256, 0, stream>>>((uint32*)B0, csr, row_ptr, (uint32*)B1, N);
    k_prop<<<pb, 256, 0, stream>>>((uint32*)B1, csr, row_ptr, (uint32*)B2, N);
    k_prop<<<pb, 256, 0, stream>>>((uint32*)B2, csr, row_ptr, (uint32*)B3, N);
    k_mfma_gemm512<true><<<gb, 256, 0, stream>>>(B0, B1, B2, B3, W1p, b1, B4, N);

    // layer 2: Y1=P*B4, Y2, Y3 -> gemm(transformed W2) -> relu -> B3
    k_prop<<<pb, 256, 0, stream>>>((uint32*)B4, csr, row_ptr, (uint32*)B0, N);
    k_prop<<<pb, 256, 0, stream>>>((uint32*)B0, csr, row_ptr, (uint32*)B1, N);
    k_prop<<<pb, 256, 0, stream>>>((uint32*)B1, csr, row_ptr, (uint32*)B2, N);
    k_mfma_gemm512<true><<<gb, 256, 0, stream>>>(B4, B0, B1, B2, W2p, b2, B3, N);

    // heads -> d_out = [mu ; logvar] fp32
    k_mfma_head<<<gb, 256, 0, stream>>>(B3, WHp, bmu, blv, (float*)d_out, N);
}